// Round 23
// baseline (175.791 us; speedup 1.0000x reference)
//
#include <hip/hip_runtime.h>

typedef unsigned short u16;
typedef unsigned int u32;
typedef __attribute__((ext_vector_type(8))) short short8;
typedef __attribute__((ext_vector_type(4))) float f32x4;

constexpr int S_ = 256, I_ = 256, C_ = 256, H_ = 8, D_ = 32, HD_ = 256;
constexpr float QSCALE = 0.17677669529663687f;  // 1/sqrt(32)

__device__ __forceinline__ float b2f(u32 u) {
  union { u32 i; float f; } x; x.i = u << 16; return x.f;
}
__device__ __forceinline__ u16 f2b(float f) {
  union { float f; u32 i; } x; x.f = f;
  u32 r = x.i + 0x7fffu + ((x.i >> 16) & 1u);
  return (u16)(r >> 16);
}
__device__ __forceinline__ uint4 pack8(const float* f) {
  uint4 r;
  r.x = (u32)f2b(f[0]) | ((u32)f2b(f[1]) << 16);
  r.y = (u32)f2b(f[2]) | ((u32)f2b(f[3]) << 16);
  r.z = (u32)f2b(f[4]) | ((u32)f2b(f[5]) << 16);
  r.w = (u32)f2b(f[6]) | ((u32)f2b(f[7]) << 16);
  return r;
}
__device__ __forceinline__ void load8f(const float* p, float* f) {
  float4 a = *reinterpret_cast<const float4*>(p);
  float4 b = *reinterpret_cast<const float4*>(p + 4);
  f[0] = a.x; f[1] = a.y; f[2] = a.z; f[3] = a.w;
  f[4] = b.x; f[5] = b.y; f[6] = b.z; f[7] = b.w;
}
__device__ __forceinline__ f32x4 mfma16(short8 a, short8 b, f32x4 c) {
  return __builtin_amdgcn_mfma_f32_16x16x32_bf16(a, b, c, 0, 0, 0);
}

// ---------------- K0: weight-pack only ----------------
__global__ void k_wpack(const float* __restrict__ wq, const float* __restrict__ wk,
                        const float* __restrict__ wv, const float* __restrict__ wg,
                        const float* __restrict__ wo, u16* __restrict__ wall2) {
  int gid = blockIdx.x * 4 + (threadIdx.x >> 6);
  int lane = threadIdx.x & 63;
  if (gid >= 640) return;
  const float* W;
  int g2;
  if (gid < 512) {
    int mat = gid >> 7;
    W = (mat == 0) ? wq : (mat == 1) ? wk : (mat == 2) ? wv : wg;
    g2 = gid & 127;
  } else {
    W = wo;
    g2 = gid - 512;
  }
  int nn = g2 & 1, kk = (g2 >> 1) & 7, ch2 = (g2 >> 4) & 1, cbi = (g2 >> 5) & 3;
  int row = cbi * 64 + ch2 * 32 + nn * 16 + (lane & 15);
  int k0 = kk * 32 + (lane >> 4) * 8;
  float f[8];
  load8f(W + (size_t)row * 256 + k0, f);
  *reinterpret_cast<uint4*>(wall2 + (size_t)gid * 512 + lane * 8) = pack8(f);
}

// ---------------- K1: fused LN-in-staging + QKVG projection ----------
// setprio on MFMA cluster; mat hoisted to a static outer loop (epilogue folds).
__global__ __launch_bounds__(256, 4) void k_qkvg(
    const float* __restrict__ m, const float* __restrict__ mask,
    const float* __restrict__ lnw, const float* __restrict__ lnb,
    const u16* __restrict__ wall2, const float* __restrict__ bg,
    u16* __restrict__ qT, u16* __restrict__ kT, u16* __restrict__ vT,
    u16* __restrict__ gT) {
  __shared__ u16 lA[64 * 256];
  int tile = blockIdx.x;  // 0..1023
  int i_col = tile >> 2, s0 = (tile & 3) * 64;
  int t = threadIdx.x;
  int rowg = t >> 5, cg = t & 31;
  float wv8[8], bv8[8];
  load8f(lnw + cg * 8, wv8);
  load8f(lnb + cg * 8, bv8);
#pragma unroll
  for (int p = 0; p < 8; ++p) {
    int row = p * 8 + rowg;
    int rg = (s0 + row) * I_ + i_col;
    float xf[8], yf[8];
    load8f(m + (size_t)rg * C_ + cg * 8, xf);
    float s1 = 0.f, s2 = 0.f;
#pragma unroll
    for (int u = 0; u < 8; ++u) { s1 += xf[u]; s2 += xf[u] * xf[u]; }
#pragma unroll
    for (int o = 16; o; o >>= 1) { s1 += __shfl_xor(s1, o); s2 += __shfl_xor(s2, o); }
    float mean = s1 * (1.f / C_);
    float var = s2 * (1.f / C_) - mean * mean;
    float rs = rsqrtf(fmaxf(var, 0.f) + 1e-5f);
    float mkv = mask[rg];
#pragma unroll
    for (int u = 0; u < 8; ++u) yf[u] = ((xf[u] - mean) * rs * wv8[u] + bv8[u]) * mkv;
    *reinterpret_cast<uint4*>(&lA[row * 256 + ((cg * 8) ^ ((row & 7) << 3))]) = pack8(yf);
  }
  __syncthreads();
  int lane = t & 63, w = t >> 6;
  int wr = (w >> 1) * 32, ch2 = w & 1, wc = ch2 * 32;
  int lr = lane & 15, lk = lane >> 4;
  f32x4 zz = {0.f, 0.f, 0.f, 0.f};
#pragma unroll
  for (int mat = 0; mat < 4; ++mat) {       // static: epilogue branches fold
    for (int cbi = 0; cbi < 4; ++cbi) {     // runtime: no code bloat
      int chunk = mat * 4 + cbi;
      int cb = cbi * 64;
      const u16* Bp = wall2 + (size_t)((chunk * 2 + ch2) * 16) * 512 + lane * 8;
      f32x4 acc[2][2] = {{zz, zz}, {zz, zz}};
      __builtin_amdgcn_s_setprio(1);
#pragma unroll
      for (int kk = 0; kk < 8; ++kk) {
        int kb = kk * 32 + lk * 8;
        int ra0 = wr + lr, ra1 = wr + 16 + lr;
        short8 a0 = *reinterpret_cast<const short8*>(&lA[ra0 * 256 + (kb ^ ((ra0 & 7) << 3))]);
        short8 a1 = *reinterpret_cast<const short8*>(&lA[ra1 * 256 + (kb ^ ((ra1 & 7) << 3))]);
        short8 b0 = *reinterpret_cast<const short8*>(Bp + (kk * 2 + 0) * 512);
        short8 b1 = *reinterpret_cast<const short8*>(Bp + (kk * 2 + 1) * 512);
        acc[0][0] = mfma16(a0, b0, acc[0][0]);
        acc[0][1] = mfma16(a0, b1, acc[0][1]);
        acc[1][0] = mfma16(a1, b0, acc[1][0]);
        acc[1][1] = mfma16(a1, b1, acc[1][1]);
      }
      __builtin_amdgcn_s_setprio(0);
#pragma unroll
      for (int mm = 0; mm < 2; ++mm) {
#pragma unroll
        for (int nn = 0; nn < 2; ++nn) {
          int colL = wc + nn * 16 + lr;
          int hd = cb + colL;
          int h = hd >> 5, d = hd & 31;
          int sbase = s0 + wr + mm * 16 + lk * 4;
          float v4[4];
#pragma unroll
          for (int r = 0; r < 4; ++r) v4[r] = acc[mm][nn][r];
          u16* dstp;
          if (mat == 0) {
#pragma unroll
            for (int r = 0; r < 4; ++r) v4[r] *= QSCALE;
            dstp = qT;
          } else if (mat == 1) {
            dstp = kT;
          } else if (mat == 2) {
            dstp = vT;
          } else {
            float bgv = bg[hd];
#pragma unroll
            for (int r = 0; r < 4; ++r) {
              float mkv = mask[(sbase + r) * I_ + i_col];
              v4[r] = mkv * (1.f / (1.f + __expf(-(v4[r] + bgv))));
            }
            dstp = gT;
          }
          uint2 pk;
          pk.x = (u32)f2b(v4[0]) | ((u32)f2b(v4[1]) << 16);
          pk.y = (u32)f2b(v4[2]) | ((u32)f2b(v4[3]) << 16);
          *reinterpret_cast<uint2*>(
              dstp + (((size_t)i_col * H_ + h) * D_ + d) * S_ + sbase) = pk;
        }
      }
    }
  }
}

// ---------------- K2: MFMA flash attention per (i,h), defer-max ----------
// qT/kT/vT/gT all [i][h][d][s]; lK and lQ transposed-in during staging.
__global__ __launch_bounds__(1024) void k_attn(
    const u16* __restrict__ qT, const u16* __restrict__ kT,
    const u16* __restrict__ vT, const u16* __restrict__ gT,
    const float* __restrict__ mask, u16* __restrict__ ows) {
  __shared__ u16 lK[256 * 40];   // [k-row s][d], +16B row pad
  __shared__ u16 lQ[256 * 40];   // [q-row s][d], +16B row pad
  __shared__ u16 lV[32 * 264];   // V^T rows, +16B pad
  __shared__ float lMk[256];
  int bid = blockIdx.x;
  int i = bid >> 3, h = bid & 7;
  int t = threadIdx.x;
  size_t base = ((size_t)i * H_ + h) * (size_t)(S_ * D_);
  {
    // K and Q: transpose-in from [d][s] -> [s][40]
    int dK = t & 31, sb = (t >> 5) * 8;
    uint4 kv4 = *reinterpret_cast<const uint4*>(kT + base + (size_t)dK * 256 + sb);
    const u16* tp = reinterpret_cast<const u16*>(&kv4);
#pragma unroll
    for (int e = 0; e < 8; ++e) lK[(sb + e) * 40 + dK] = tp[e];
    uint4 qv4 = *reinterpret_cast<const uint4*>(qT + base + (size_t)dK * 256 + sb);
    const u16* tq = reinterpret_cast<const u16*>(&qv4);
#pragma unroll
    for (int e = 0; e < 8; ++e) lQ[(sb + e) * 40 + dK] = tq[e];
    int d = t >> 5, p2 = t & 31;
    *reinterpret_cast<uint4*>(&lV[d * 264 + p2 * 8]) =
        *reinterpret_cast<const uint4*>(vT + base + d * 256 + p2 * 8);
    if (t < 256) lMk[t] = mask[t * I_ + i];
  }
  __syncthreads();
  int lane = t & 63;
  int wvid = t >> 6;
  int lq = lane & 15, g = lane >> 4;
  int qbase = wvid * 16;
  short8 qf = *reinterpret_cast<const short8*>(&lQ[(qbase + lq) * 40 + g * 8]);
  f32x4 zz = {0.f, 0.f, 0.f, 0.f};
  f32x4 o0 = zz, o1 = zz;
  float mcur = -1e30f, sumd = 0.f;
  int addrP0 = (lq + ((g & 1) * 2 + 0) * 16) * 4;
  int addrP1 = (lq + ((g & 1) * 2 + 1) * 16) * 4;
  int aC0 = (g * 4 + 0) * 4, aC1 = (g * 4 + 1) * 4;
  int aC2 = (g * 4 + 2) * 4, aC3 = (g * 4 + 3) * 4;
#pragma unroll
  for (int ks = 0; ks < 8; ++ks) {
    int k0 = ks * 32;
    short8 kf0 = *reinterpret_cast<const short8*>(&lK[(k0 + lq) * 40 + g * 8]);
    short8 kf1 = *reinterpret_cast<const short8*>(&lK[(k0 + 16 + lq) * 40 + g * 8]);
    f32x4 s0 = mfma16(kf0, qf, zz);
    f32x4 s1 = mfma16(kf1, qf, zz);
    float4 mk0 = *reinterpret_cast<const float4*>(&lMk[k0 + g * 4]);
    float4 mk1 = *reinterpret_cast<const float4*>(&lMk[k0 + 16 + g * 4]);
    float sv[8];
    sv[0] = mk0.x > 0.f ? s0[0] : -1e9f;
    sv[1] = mk0.y > 0.f ? s0[1] : -1e9f;
    sv[2] = mk0.z > 0.f ? s0[2] : -1e9f;
    sv[3] = mk0.w > 0.f ? s0[3] : -1e9f;
    sv[4] = mk1.x > 0.f ? s1[0] : -1e9f;
    sv[5] = mk1.y > 0.f ? s1[1] : -1e9f;
    sv[6] = mk1.z > 0.f ? s1[2] : -1e9f;
    sv[7] = mk1.w > 0.f ? s1[3] : -1e9f;
    float tmax = fmaxf(fmaxf(fmaxf(sv[0], sv[1]), fmaxf(sv[2], sv[3])),
                       fmaxf(fmaxf(sv[4], sv[5]), fmaxf(sv[6], sv[7])));
    tmax = fmaxf(tmax, __shfl_xor(tmax, 16));
    tmax = fmaxf(tmax, __shfl_xor(tmax, 32));
    bool skip = __all(tmax <= mcur + 8.0f);
    if (!skip) {
      float mnew = fmaxf(mcur, tmax);
      float c = __expf(mcur - mnew);
      mcur = mnew;
      sumd *= c;
      float co0 = __int_as_float(__builtin_amdgcn_ds_bpermute(aC0, __float_as_int(c)));
      float co1 = __int_as_float(__builtin_amdgcn_ds_bpermute(aC1, __float_as_int(c)));
      float co2 = __int_as_float(__builtin_amdgcn_ds_bpermute(aC2, __float_as_int(c)));
      float co3 = __int_as_float(__builtin_amdgcn_ds_bpermute(aC3, __float_as_int(c)));
      o0[0] *= co0; o0[1] *= co1; o0[2] *= co2; o0[3] *= co3;
      o1[0] *= co0; o1[1] *= co1; o1[2] *= co2; o1[3] *= co3;
    }
    float p[8];
#pragma unroll
    for (int j = 0; j < 8; ++j) p[j] = __expf(sv[j] - mcur);
    sumd += ((p[0] + p[1]) + (p[2] + p[3])) + ((p[4] + p[5]) + (p[6] + p[7]));
    u32 pk00 = (u32)f2b(p[0]) | ((u32)f2b(p[1]) << 16);
    u32 pk01 = (u32)f2b(p[2]) | ((u32)f2b(p[3]) << 16);
    u32 pk10 = (u32)f2b(p[4]) | ((u32)f2b(p[5]) << 16);
    u32 pk11 = (u32)f2b(p[6]) | ((u32)f2b(p[7]) << 16);
    int b00 = __builtin_amdgcn_ds_bpermute(addrP0, (int)pk00);
    int b10 = __builtin_amdgcn_ds_bpermute(addrP0, (int)pk10);
    int b01 = __builtin_amdgcn_ds_bpermute(addrP0, (int)pk01);
    int b11 = __builtin_amdgcn_ds_bpermute(addrP0, (int)pk11);
    int b02 = __builtin_amdgcn_ds_bpermute(addrP1, (int)pk00);
    int b12 = __builtin_amdgcn_ds_bpermute(addrP1, (int)pk10);
    int b03 = __builtin_amdgcn_ds_bpermute(addrP1, (int)pk01);
    int b13 = __builtin_amdgcn_ds_bpermute(addrP1, (int)pk11);
    union { int u[4]; short8 s8; } pu;
    bool lo = (g < 2);
    pu.u[0] = lo ? b00 : b10;
    pu.u[1] = lo ? b01 : b11;
    pu.u[2] = lo ? b02 : b12;
    pu.u[3] = lo ? b03 : b13;
    short8 vf0 = *reinterpret_cast<const short8*>(&lV[lq * 264 + k0 + g * 8]);
    short8 vf1 = *reinterpret_cast<const short8*>(&lV[(16 + lq) * 264 + k0 + g * 8]);
    o0 = mfma16(pu.s8, vf0, o0);
    o1 = mfma16(pu.s8, vf1, o1);
  }
  float s2 = sumd + __shfl_xor(sumd, 16);
  float tot = s2 + __shfl_xor(s2, 32);
  float iv = 1.f / tot;
  float ivo[4];
  ivo[0] = __int_as_float(__builtin_amdgcn_ds_bpermute(aC0, __float_as_int(iv)));
  ivo[1] = __int_as_float(__builtin_amdgcn_ds_bpermute(aC1, __float_as_int(iv)));
  ivo[2] = __int_as_float(__builtin_amdgcn_ds_bpermute(aC2, __float_as_int(iv)));
  ivo[3] = __int_as_float(__builtin_amdgcn_ds_bpermute(aC3, __float_as_int(iv)));
#pragma unroll
  for (int r = 0; r < 4; ++r) {
    int row = qbase + g * 4 + r;
    float g0 = b2f((u32)gT[base + (size_t)lq * 256 + row]);
    float g1 = b2f((u32)gT[base + (size_t)(lq + 16) * 256 + row]);
    ows[base + (size_t)row * D_ + lq] = f2b(o0[r] * ivo[r] * g0);
    ows[base + (size_t)row * D_ + lq + 16] = f2b(o1[r] * ivo[r] * g1);
  }
}

// ---------------- K3: output projection (512 thr / 8 waves, round-19 form) ----
__global__ __launch_bounds__(512) void k_oproj(const u16* __restrict__ ows,
                                               const u16* __restrict__ wall2,
                                               const float* __restrict__ bo,
                                               float* __restrict__ out) {
  __shared__ u16 lA[64 * 256];
  int tile = blockIdx.x;  // 0..1023
  int r0 = tile * 64;
  int t = threadIdx.x;
  int rowg = t >> 5, cg = t & 31;
  int hh = cg >> 2, d0 = (cg & 3) * 8;
#pragma unroll
  for (int p = 0; p < 4; ++p) {
    int row = p * 16 + rowg;
    int rg = r0 + row;
    int ii = rg >> 8, ss = rg & 255;
    *reinterpret_cast<uint4*>(&lA[row * 256 + ((cg * 8) ^ ((row & 7) << 3))]) =
        *reinterpret_cast<const uint4*>(ows + (((size_t)ii * H_ + hh) * S_ + ss) * D_ + d0);
  }
  __syncthreads();
  int lane = t & 63, w = t >> 6;
  int wr = (w >> 2) * 32, ch4 = w & 3;
  int lr = lane & 15, lk = lane >> 4;
  f32x4 zz = {0.f, 0.f, 0.f, 0.f};
  for (int chunk = 0; chunk < 4; ++chunk) {
    int cb = chunk * 64;
    const u16* Bp =
        wall2 + (size_t)(512 + (chunk * 2 + (ch4 >> 1)) * 16 + (ch4 & 1)) * 512 + lane * 8;
    f32x4 acc0 = zz, acc1 = zz;
#pragma unroll
    for (int kk = 0; kk < 8; ++kk) {
      int kb = kk * 32 + lk * 8;
      int ra0 = wr + lr, ra1 = wr + 16 + lr;
      short8 a0 = *reinterpret_cast<const short8*>(&lA[ra0 * 256 + (kb ^ ((ra0 & 7) << 3))]);
      short8 a1 = *reinterpret_cast<const short8*>(&lA[ra1 * 256 + (kb ^ ((ra1 & 7) << 3))]);
      short8 b0 = *reinterpret_cast<const short8*>(Bp + kk * 1024);
      acc0 = mfma16(a0, b0, acc0);
      acc1 = mfma16(a1, b0, acc1);
    }
    int ch = cb + ch4 * 16 + lr;
    float bov = bo[ch];
#pragma unroll
    for (int mm = 0; mm < 2; ++mm) {
      const f32x4& acc = (mm == 0) ? acc0 : acc1;
#pragma unroll
      for (int r = 0; r < 4; ++r) {
        int rg = r0 + wr + mm * 16 + lk * 4 + r;
        int ii = rg >> 8;
        int ss = rg & 255;
        out[((size_t)ss * I_ + ii) * C_ + ch] = acc[r] + bov;
      }
    }
  }
}

extern "C" void kernel_launch(void* const* d_in, const int* in_sizes, int n_in,
                              void* d_out, int out_size, void* d_ws, size_t ws_size,
                              hipStream_t stream) {
  const float *m, *mask, *lnw, *lnb, *wq, *wk, *wv, *wg, *bg, *wo, *bo;
  if (in_sizes[0] > 1000000) {  // dict order
    m = (const float*)d_in[0]; mask = (const float*)d_in[1];
    lnw = (const float*)d_in[2]; lnb = (const float*)d_in[3];
    wq = (const float*)d_in[4]; wk = (const float*)d_in[5];
    wv = (const float*)d_in[6]; wg = (const float*)d_in[7];
    bg = (const float*)d_in[8]; wo = (const float*)d_in[9];
    bo = (const float*)d_in[10];
  } else {  // alphabetical fallback
    bg = (const float*)d_in[0]; bo = (const float*)d_in[1];
    lnb = (const float*)d_in[2]; lnw = (const float*)d_in[3];
    m = (const float*)d_in[4]; mask = (const float*)d_in[5];
    wg = (const float*)d_in[6]; wk = (const float*)d_in[7];
    wo = (const float*)d_in[8]; wq = (const float*)d_in[9];
    wv = (const float*)d_in[10];
  }
  float* out = (float*)d_out;

  const size_t SZ = (size_t)S_ * I_ * C_;  // 16,777,216
  u16* qT = (u16*)d_ws;    // Q^T [i][h][d][s], pre-scaled
  u16* kT = qT + SZ;       // K^T [i][h][d][s]
  u16* vT = kT + SZ;       // V^T [i][h][d][s]
  u16* gT = vT + SZ;       // gate^T [i][h][d][s]
  u16* ows = gT + SZ;      // O [i][h][s][d]
  u16* wall2 = ows + SZ;   // fragment-ordered weights: 640 groups x 512 u16

  k_wpack<<<160, 256, 0, stream>>>(wq, wk, wv, wg, wo, wall2);
  k_qkvg<<<1024, 256, 0, stream>>>(m, mask, lnw, lnb, wall2, bg, qT, kT, vT, gT);
  k_attn<<<2048, 1024, 0, stream>>>(qT, kT, vT, gT, mask, ows);
  k_oproj<<<1024, 512, 0, stream>>>(ows, wall2, bo, out);
}

// Round 24
// 174.694 us; speedup vs baseline: 1.0063x; 1.0063x over previous
//
#include <hip/hip_runtime.h>

typedef unsigned short u16;
typedef unsigned int u32;
typedef __attribute__((ext_vector_type(8))) short short8;
typedef __attribute__((ext_vector_type(4))) float f32x4;

constexpr int S_ = 256, I_ = 256, C_ = 256, H_ = 8, D_ = 32, HD_ = 256;
constexpr float QSCALE = 0.17677669529663687f;  // 1/sqrt(32)

__device__ __forceinline__ float b2f(u32 u) {
  union { u32 i; float f; } x; x.i = u << 16; return x.f;
}
__device__ __forceinline__ u16 f2b(float f) {
  union { float f; u32 i; } x; x.f = f;
  u32 r = x.i + 0x7fffu + ((x.i >> 16) & 1u);
  return (u16)(r >> 16);
}
__device__ __forceinline__ uint4 pack8(const float* f) {
  uint4 r;
  r.x = (u32)f2b(f[0]) | ((u32)f2b(f[1]) << 16);
  r.y = (u32)f2b(f[2]) | ((u32)f2b(f[3]) << 16);
  r.z = (u32)f2b(f[4]) | ((u32)f2b(f[5]) << 16);
  r.w = (u32)f2b(f[6]) | ((u32)f2b(f[7]) << 16);
  return r;
}
__device__ __forceinline__ void load8f(const float* p, float* f) {
  float4 a = *reinterpret_cast<const float4*>(p);
  float4 b = *reinterpret_cast<const float4*>(p + 4);
  f[0] = a.x; f[1] = a.y; f[2] = a.z; f[3] = a.w;
  f[4] = b.x; f[5] = b.y; f[6] = b.z; f[7] = b.w;
}
__device__ __forceinline__ f32x4 mfma16(short8 a, short8 b, f32x4 c) {
  return __builtin_amdgcn_mfma_f32_16x16x32_bf16(a, b, c, 0, 0, 0);
}

// ---------------- K0: weight-pack only ----------------
__global__ void k_wpack(const float* __restrict__ wq, const float* __restrict__ wk,
                        const float* __restrict__ wv, const float* __restrict__ wg,
                        const float* __restrict__ wo, u16* __restrict__ wall2) {
  int gid = blockIdx.x * 4 + (threadIdx.x >> 6);
  int lane = threadIdx.x & 63;
  if (gid >= 640) return;
  const float* W;
  int g2;
  if (gid < 512) {
    int mat = gid >> 7;
    W = (mat == 0) ? wq : (mat == 1) ? wk : (mat == 2) ? wv : wg;
    g2 = gid & 127;
  } else {
    W = wo;
    g2 = gid - 512;
  }
  int nn = g2 & 1, kk = (g2 >> 1) & 7, ch2 = (g2 >> 4) & 1, cbi = (g2 >> 5) & 3;
  int row = cbi * 64 + ch2 * 32 + nn * 16 + (lane & 15);
  int k0 = kk * 32 + (lane >> 4) * 8;
  float f[8];
  load8f(W + (size_t)row * 256 + k0, f);
  *reinterpret_cast<uint4*>(wall2 + (size_t)gid * 512 + lane * 8) = pack8(f);
}

// ---------------- K1: fused LN-in-staging + QKVG projection ----------
// setprio on MFMA cluster; mat hoisted to a static outer loop (epilogue folds).
__global__ __launch_bounds__(256, 4) void k_qkvg(
    const float* __restrict__ m, const float* __restrict__ mask,
    const float* __restrict__ lnw, const float* __restrict__ lnb,
    const u16* __restrict__ wall2, const float* __restrict__ bg,
    u16* __restrict__ qT, u16* __restrict__ kT, u16* __restrict__ vT,
    u16* __restrict__ gT) {
  __shared__ u16 lA[64 * 256];
  int tile = blockIdx.x;  // 0..1023
  int i_col = tile >> 2, s0 = (tile & 3) * 64;
  int t = threadIdx.x;
  int rowg = t >> 5, cg = t & 31;
  float wv8[8], bv8[8];
  load8f(lnw + cg * 8, wv8);
  load8f(lnb + cg * 8, bv8);
#pragma unroll
  for (int p = 0; p < 8; ++p) {
    int row = p * 8 + rowg;
    int rg = (s0 + row) * I_ + i_col;
    float xf[8], yf[8];
    load8f(m + (size_t)rg * C_ + cg * 8, xf);
    float s1 = 0.f, s2 = 0.f;
#pragma unroll
    for (int u = 0; u < 8; ++u) { s1 += xf[u]; s2 += xf[u] * xf[u]; }
#pragma unroll
    for (int o = 16; o; o >>= 1) { s1 += __shfl_xor(s1, o); s2 += __shfl_xor(s2, o); }
    float mean = s1 * (1.f / C_);
    float var = s2 * (1.f / C_) - mean * mean;
    float rs = rsqrtf(fmaxf(var, 0.f) + 1e-5f);
    float mkv = mask[rg];
#pragma unroll
    for (int u = 0; u < 8; ++u) yf[u] = ((xf[u] - mean) * rs * wv8[u] + bv8[u]) * mkv;
    *reinterpret_cast<uint4*>(&lA[row * 256 + ((cg * 8) ^ ((row & 7) << 3))]) = pack8(yf);
  }
  __syncthreads();
  int lane = t & 63, w = t >> 6;
  int wr = (w >> 1) * 32, ch2 = w & 1, wc = ch2 * 32;
  int lr = lane & 15, lk = lane >> 4;
  f32x4 zz = {0.f, 0.f, 0.f, 0.f};
#pragma unroll
  for (int mat = 0; mat < 4; ++mat) {       // static: epilogue branches fold
    for (int cbi = 0; cbi < 4; ++cbi) {     // runtime: no code bloat
      int chunk = mat * 4 + cbi;
      int cb = cbi * 64;
      const u16* Bp = wall2 + (size_t)((chunk * 2 + ch2) * 16) * 512 + lane * 8;
      f32x4 acc[2][2] = {{zz, zz}, {zz, zz}};
      __builtin_amdgcn_s_setprio(1);
#pragma unroll
      for (int kk = 0; kk < 8; ++kk) {
        int kb = kk * 32 + lk * 8;
        int ra0 = wr + lr, ra1 = wr + 16 + lr;
        short8 a0 = *reinterpret_cast<const short8*>(&lA[ra0 * 256 + (kb ^ ((ra0 & 7) << 3))]);
        short8 a1 = *reinterpret_cast<const short8*>(&lA[ra1 * 256 + (kb ^ ((ra1 & 7) << 3))]);
        short8 b0 = *reinterpret_cast<const short8*>(Bp + (kk * 2 + 0) * 512);
        short8 b1 = *reinterpret_cast<const short8*>(Bp + (kk * 2 + 1) * 512);
        acc[0][0] = mfma16(a0, b0, acc[0][0]);
        acc[0][1] = mfma16(a0, b1, acc[0][1]);
        acc[1][0] = mfma16(a1, b0, acc[1][0]);
        acc[1][1] = mfma16(a1, b1, acc[1][1]);
      }
      __builtin_amdgcn_s_setprio(0);
#pragma unroll
      for (int mm = 0; mm < 2; ++mm) {
#pragma unroll
        for (int nn = 0; nn < 2; ++nn) {
          int colL = wc + nn * 16 + lr;
          int hd = cb + colL;
          int h = hd >> 5, d = hd & 31;
          int sbase = s0 + wr + mm * 16 + lk * 4;
          float v4[4];
#pragma unroll
          for (int r = 0; r < 4; ++r) v4[r] = acc[mm][nn][r];
          u16* dstp;
          if (mat == 0) {
#pragma unroll
            for (int r = 0; r < 4; ++r) v4[r] *= QSCALE;
            dstp = qT;
          } else if (mat == 1) {
            dstp = kT;
          } else if (mat == 2) {
            dstp = vT;
          } else {
            float bgv = bg[hd];
#pragma unroll
            for (int r = 0; r < 4; ++r) {
              float mkv = mask[(sbase + r) * I_ + i_col];
              v4[r] = mkv * (1.f / (1.f + __expf(-(v4[r] + bgv))));
            }
            dstp = gT;
          }
          uint2 pk;
          pk.x = (u32)f2b(v4[0]) | ((u32)f2b(v4[1]) << 16);
          pk.y = (u32)f2b(v4[2]) | ((u32)f2b(v4[3]) << 16);
          *reinterpret_cast<uint2*>(
              dstp + (((size_t)i_col * H_ + h) * D_ + d) * S_ + sbase) = pk;
        }
      }
    }
  }
}

// ---------------- K2: MFMA flash attention per (i,h), defer-max (round-22 form) ----
__global__ __launch_bounds__(1024) void k_attn(
    const u16* __restrict__ qT, const u16* __restrict__ kT,
    const u16* __restrict__ vT, const u16* __restrict__ gT,
    const float* __restrict__ mask, u16* __restrict__ ows) {
  __shared__ u16 lK[256 * 40];   // [k-row s][d], +16B row pad
  __shared__ u16 lV[32 * 264];   // V^T rows, +16B pad
  __shared__ float lMk[256];
  int bid = blockIdx.x;
  int i = bid >> 3, h = bid & 7;
  int t = threadIdx.x;
  size_t base = ((size_t)i * H_ + h) * (size_t)(S_ * D_);
  {
    // K: transpose-in from kT[d][s] -> lK[s][40]
    int dK = t & 31, sb = (t >> 5) * 8;
    uint4 kv4 = *reinterpret_cast<const uint4*>(kT + base + (size_t)dK * 256 + sb);
    const u16* tp = reinterpret_cast<const u16*>(&kv4);
#pragma unroll
    for (int e = 0; e < 8; ++e) lK[(sb + e) * 40 + dK] = tp[e];
    int d = t >> 5, p2 = t & 31;
    *reinterpret_cast<uint4*>(&lV[d * 264 + p2 * 8]) =
        *reinterpret_cast<const uint4*>(vT + base + d * 256 + p2 * 8);
    if (t < 256) lMk[t] = mask[t * I_ + i];
  }
  __syncthreads();
  int lane = t & 63;
  int wvid = t >> 6;
  int lq = lane & 15, g = lane >> 4;
  int qbase = wvid * 16;
  short8 qf;
  {
    const u16* Q = qT + base;
    int s = qbase + lq;
#pragma unroll
    for (int e = 0; e < 8; ++e) qf[e] = (short)Q[(g * 8 + e) * 256 + s];
  }
  f32x4 zz = {0.f, 0.f, 0.f, 0.f};
  f32x4 o0 = zz, o1 = zz;
  float mcur = -1e30f, sumd = 0.f;
  int addrP0 = (lq + ((g & 1) * 2 + 0) * 16) * 4;
  int addrP1 = (lq + ((g & 1) * 2 + 1) * 16) * 4;
  int aC0 = (g * 4 + 0) * 4, aC1 = (g * 4 + 1) * 4;
  int aC2 = (g * 4 + 2) * 4, aC3 = (g * 4 + 3) * 4;
#pragma unroll
  for (int ks = 0; ks < 8; ++ks) {
    int k0 = ks * 32;
    short8 kf0 = *reinterpret_cast<const short8*>(&lK[(k0 + lq) * 40 + g * 8]);
    short8 kf1 = *reinterpret_cast<const short8*>(&lK[(k0 + 16 + lq) * 40 + g * 8]);
    f32x4 s0 = mfma16(kf0, qf, zz);
    f32x4 s1 = mfma16(kf1, qf, zz);
    float4 mk0 = *reinterpret_cast<const float4*>(&lMk[k0 + g * 4]);
    float4 mk1 = *reinterpret_cast<const float4*>(&lMk[k0 + 16 + g * 4]);
    float sv[8];
    sv[0] = mk0.x > 0.f ? s0[0] : -1e9f;
    sv[1] = mk0.y > 0.f ? s0[1] : -1e9f;
    sv[2] = mk0.z > 0.f ? s0[2] : -1e9f;
    sv[3] = mk0.w > 0.f ? s0[3] : -1e9f;
    sv[4] = mk1.x > 0.f ? s1[0] : -1e9f;
    sv[5] = mk1.y > 0.f ? s1[1] : -1e9f;
    sv[6] = mk1.z > 0.f ? s1[2] : -1e9f;
    sv[7] = mk1.w > 0.f ? s1[3] : -1e9f;
    float tmax = fmaxf(fmaxf(fmaxf(sv[0], sv[1]), fmaxf(sv[2], sv[3])),
                       fmaxf(fmaxf(sv[4], sv[5]), fmaxf(sv[6], sv[7])));
    tmax = fmaxf(tmax, __shfl_xor(tmax, 16));
    tmax = fmaxf(tmax, __shfl_xor(tmax, 32));
    bool skip = __all(tmax <= mcur + 8.0f);
    if (!skip) {
      float mnew = fmaxf(mcur, tmax);
      float c = __expf(mcur - mnew);
      mcur = mnew;
      sumd *= c;
      float co0 = __int_as_float(__builtin_amdgcn_ds_bpermute(aC0, __float_as_int(c)));
      float co1 = __int_as_float(__builtin_amdgcn_ds_bpermute(aC1, __float_as_int(c)));
      float co2 = __int_as_float(__builtin_amdgcn_ds_bpermute(aC2, __float_as_int(c)));
      float co3 = __int_as_float(__builtin_amdgcn_ds_bpermute(aC3, __float_as_int(c)));
      o0[0] *= co0; o0[1] *= co1; o0[2] *= co2; o0[3] *= co3;
      o1[0] *= co0; o1[1] *= co1; o1[2] *= co2; o1[3] *= co3;
    }
    float p[8];
#pragma unroll
    for (int j = 0; j < 8; ++j) p[j] = __expf(sv[j] - mcur);
    sumd += ((p[0] + p[1]) + (p[2] + p[3])) + ((p[4] + p[5]) + (p[6] + p[7]));
    u32 pk00 = (u32)f2b(p[0]) | ((u32)f2b(p[1]) << 16);
    u32 pk01 = (u32)f2b(p[2]) | ((u32)f2b(p[3]) << 16);
    u32 pk10 = (u32)f2b(p[4]) | ((u32)f2b(p[5]) << 16);
    u32 pk11 = (u32)f2b(p[6]) | ((u32)f2b(p[7]) << 16);
    int b00 = __builtin_amdgcn_ds_bpermute(addrP0, (int)pk00);
    int b10 = __builtin_amdgcn_ds_bpermute(addrP0, (int)pk10);
    int b01 = __builtin_amdgcn_ds_bpermute(addrP0, (int)pk01);
    int b11 = __builtin_amdgcn_ds_bpermute(addrP0, (int)pk11);
    int b02 = __builtin_amdgcn_ds_bpermute(addrP1, (int)pk00);
    int b12 = __builtin_amdgcn_ds_bpermute(addrP1, (int)pk10);
    int b03 = __builtin_amdgcn_ds_bpermute(addrP1, (int)pk01);
    int b13 = __builtin_amdgcn_ds_bpermute(addrP1, (int)pk11);
    union { int u[4]; short8 s8; } pu;
    bool lo = (g < 2);
    pu.u[0] = lo ? b00 : b10;
    pu.u[1] = lo ? b01 : b11;
    pu.u[2] = lo ? b02 : b12;
    pu.u[3] = lo ? b03 : b13;
    short8 vf0 = *reinterpret_cast<const short8*>(&lV[lq * 264 + k0 + g * 8]);
    short8 vf1 = *reinterpret_cast<const short8*>(&lV[(16 + lq) * 264 + k0 + g * 8]);
    o0 = mfma16(pu.s8, vf0, o0);
    o1 = mfma16(pu.s8, vf1, o1);
  }
  float s2 = sumd + __shfl_xor(sumd, 16);
  float tot = s2 + __shfl_xor(s2, 32);
  float iv = 1.f / tot;
  float ivo[4];
  ivo[0] = __int_as_float(__builtin_amdgcn_ds_bpermute(aC0, __float_as_int(iv)));
  ivo[1] = __int_as_float(__builtin_amdgcn_ds_bpermute(aC1, __float_as_int(iv)));
  ivo[2] = __int_as_float(__builtin_amdgcn_ds_bpermute(aC2, __float_as_int(iv)));
  ivo[3] = __int_as_float(__builtin_amdgcn_ds_bpermute(aC3, __float_as_int(iv)));
#pragma unroll
  for (int r = 0; r < 4; ++r) {
    int row = qbase + g * 4 + r;
    float g0 = b2f((u32)gT[base + (size_t)lq * 256 + row]);
    float g1 = b2f((u32)gT[base + (size_t)(lq + 16) * 256 + row]);
    ows[base + (size_t)row * D_ + lq] = f2b(o0[r] * ivo[r] * g0);
    ows[base + (size_t)row * D_ + lq + 16] = f2b(o1[r] * ivo[r] * g1);
  }
}

// ---------------- K3: output projection (512 thr / 8 waves, round-19 form) ----
__global__ __launch_bounds__(512) void k_oproj(const u16* __restrict__ ows,
                                               const u16* __restrict__ wall2,
                                               const float* __restrict__ bo,
                                               float* __restrict__ out) {
  __shared__ u16 lA[64 * 256];
  int tile = blockIdx.x;  // 0..1023
  int r0 = tile * 64;
  int t = threadIdx.x;
  int rowg = t >> 5, cg = t & 31;
  int hh = cg >> 2, d0 = (cg & 3) * 8;
#pragma unroll
  for (int p = 0; p < 4; ++p) {
    int row = p * 16 + rowg;
    int rg = r0 + row;
    int ii = rg >> 8, ss = rg & 255;
    *reinterpret_cast<uint4*>(&lA[row * 256 + ((cg * 8) ^ ((row & 7) << 3))]) =
        *reinterpret_cast<const uint4*>(ows + (((size_t)ii * H_ + hh) * S_ + ss) * D_ + d0);
  }
  __syncthreads();
  int lane = t & 63, w = t >> 6;
  int wr = (w >> 2) * 32, ch4 = w & 3;
  int lr = lane & 15, lk = lane >> 4;
  f32x4 zz = {0.f, 0.f, 0.f, 0.f};
  for (int chunk = 0; chunk < 4; ++chunk) {
    int cb = chunk * 64;
    const u16* Bp =
        wall2 + (size_t)(512 + (chunk * 2 + (ch4 >> 1)) * 16 + (ch4 & 1)) * 512 + lane * 8;
    f32x4 acc0 = zz, acc1 = zz;
#pragma unroll
    for (int kk = 0; kk < 8; ++kk) {
      int kb = kk * 32 + lk * 8;
      int ra0 = wr + lr, ra1 = wr + 16 + lr;
      short8 a0 = *reinterpret_cast<const short8*>(&lA[ra0 * 256 + (kb ^ ((ra0 & 7) << 3))]);
      short8 a1 = *reinterpret_cast<const short8*>(&lA[ra1 * 256 + (kb ^ ((ra1 & 7) << 3))]);
      short8 b0 = *reinterpret_cast<const short8*>(Bp + kk * 1024);
      acc0 = mfma16(a0, b0, acc0);
      acc1 = mfma16(a1, b0, acc1);
    }
    int ch = cb + ch4 * 16 + lr;
    float bov = bo[ch];
#pragma unroll
    for (int mm = 0; mm < 2; ++mm) {
      const f32x4& acc = (mm == 0) ? acc0 : acc1;
#pragma unroll
      for (int r = 0; r < 4; ++r) {
        int rg = r0 + wr + mm * 16 + lk * 4 + r;
        int ii = rg >> 8;
        int ss = rg & 255;
        out[((size_t)ss * I_ + ii) * C_ + ch] = acc[r] + bov;
      }
    }
  }
}

extern "C" void kernel_launch(void* const* d_in, const int* in_sizes, int n_in,
                              void* d_out, int out_size, void* d_ws, size_t ws_size,
                              hipStream_t stream) {
  const float *m, *mask, *lnw, *lnb, *wq, *wk, *wv, *wg, *bg, *wo, *bo;
  if (in_sizes[0] > 1000000) {  // dict order
    m = (const float*)d_in[0]; mask = (const float*)d_in[1];
    lnw = (const float*)d_in[2]; lnb = (const float*)d_in[3];
    wq = (const float*)d_in[4]; wk = (const float*)d_in[5];
    wv = (const float*)d_in[6]; wg = (const float*)d_in[7];
    bg = (const float*)d_in[8]; wo = (const float*)d_in[9];
    bo = (const float*)d_in[10];
  } else {  // alphabetical fallback
    bg = (const float*)d_in[0]; bo = (const float*)d_in[1];
    lnb = (const float*)d_in[2]; lnw = (const float*)d_in[3];
    m = (const float*)d_in[4]; mask = (const float*)d_in[5];
    wg = (const float*)d_in[6]; wk = (const float*)d_in[7];
    wo = (const float*)d_in[8]; wq = (const float*)d_in[9];
    wv = (const float*)d_in[10];
  }
  float* out = (float*)d_out;

  const size_t SZ = (size_t)S_ * I_ * C_;  // 16,777,216
  u16* qT = (u16*)d_ws;    // Q^T [i][h][d][s], pre-scaled
  u16* kT = qT + SZ;       // K^T [i][h][d][s]
  u16* vT = kT + SZ;       // V^T [i][h][d][s]
  u16* gT = vT + SZ;       // gate^T [i][h][d][s]
  u16* ows = gT + SZ;      // O [i][h][s][d]
  u16* wall2 = ows + SZ;   // fragment-ordered weights: 640 groups x 512 u16

  k_wpack<<<160, 256, 0, stream>>>(wq, wk, wv, wg, wo, wall2);
  k_qkvg<<<1024, 256, 0, stream>>>(m, mask, lnw, lnb, wall2, bg, qT, kT, vT, gT);
  k_attn<<<2048, 1024, 0, stream>>>(qT, kT, vT, gT, mask, ows);
  k_oproj<<<1024, 512, 0, stream>>>(ows, wall2, bo, out);
}